// Round 13
// baseline (827.925 us; speedup 1.0000x reference)
//
#include <hip/hip_runtime.h>
#include <cstdint>
#include <cstddef>

typedef unsigned short u16;
typedef __attribute__((ext_vector_type(8))) short s16x8;
typedef __attribute__((ext_vector_type(4))) float f32x4;

#define NQ   8192
#define TT   512
#define STOK 32

__device__ __forceinline__ float b2f(u16 u) {
    return __uint_as_float(((uint32_t)u) << 16);
}
__device__ __forceinline__ u16 f2b(float f) {
    uint32_t x = __float_as_uint(f);
    uint32_t r = (x + 0x7FFFu + ((x >> 16) & 1u)) >> 16;
    return (u16)r;
}
__device__ __forceinline__ float silu_f(float x) { return x / (1.f + expf(-x)); }

__global__ __launch_bounds__(256) void const_kernel(float v, float* __restrict__ out) {
    int i = blockIdx.x * 256 + threadIdx.x;
    if (i < NQ) out[i] = v;
}

// ---------------------------------------------------------------------------
// features (verified): FIN fp32 [NQ,160] (cols 152..159 = 0), IDX
// ---------------------------------------------------------------------------
__global__ __launch_bounds__(256) void feat32_kernel(
    const float* __restrict__ xy, const float* __restrict__ t_q,
    const int* __restrict__ c, const float* __restrict__ st,
    const float* __restrict__ B, const float* __restrict__ tw,
    const float* __restrict__ tb, const float* __restrict__ ce,
    float* __restrict__ FIN, int* __restrict__ IDX) {
    int n = blockIdx.x, t = threadIdx.x;
    float tq = t_q[n];
    int lo = 0, hi = TT;
    while (lo < hi) {
        int mid = (lo + hi) >> 1;
        if (st[mid] <= tq) lo = mid + 1; else hi = mid;
    }
    int idx = lo - 1;
    if (idx < 0) idx = 0;
    float dt = tq - st[idx];
    if (dt < 0.f) dt = 0.f;
    if (t == 0) IDX[n] = idx;
    float x = xy[2 * n], y = xy[2 * n + 1];
    size_t base = (size_t)n * 160;
    if (t < 64) { float p = x * B[t] + y * B[64 + t]; FIN[base + t] = cosf(p); }
    else if (t < 128) { int j = t - 64; float p = x * B[j] + y * B[64 + j]; FIN[base + t] = sinf(p); }
    else if (t < 144) { int j = t - 128; FIN[base + t] = dt * tw[j] + tb[j]; }
    else if (t < 152) { int j = t - 144; FIN[base + t] = ce[c[n] * 8 + j]; }
    else if (t < 160) { FIN[base + t] = 0.f; }
}

// pad trunk_in_w [256,152] -> [256,160] fp32
__global__ __launch_bounds__(256) void padw32_kernel(const float* __restrict__ w,
                                                     float* __restrict__ wp) {
    int i = blockIdx.x * 256 + threadIdx.x;
    if (i < 256 * 160) {
        int r = i / 160, k = i % 160;
        wp[i] = (k < 152) ? w[r * 152 + k] : 0.f;
    }
}

// ---------------------------------------------------------------------------
// fold token projection into K/V weights (exact identity, fp32)
// ---------------------------------------------------------------------------
__global__ __launch_bounds__(256) void combine_kv32(
    const float* __restrict__ aiw, const float* __restrict__ aib,
    const float* __restrict__ btw, const float* __restrict__ btb,
    float* __restrict__ WKV, float* __restrict__ bkv) {
    int kv = blockIdx.x >> 8, m = blockIdx.x & 255;
    int d = threadIdx.x;
    __shared__ float wrow[256];
    wrow[d] = aiw[(size_t)(kv + 1) * 65536 + (size_t)m * 256 + d];
    __syncthreads();
    float acc = 0.f;
#pragma unroll 8
    for (int o = 0; o < 256; o++) acc += wrow[o] * btw[(size_t)o * 256 + d];
    WKV[(size_t)kv * 65536 + (size_t)m * 256 + d] = acc;
    float pb = wrow[d] * btb[d];
#pragma unroll
    for (int mm = 32; mm >= 1; mm >>= 1) pb += __shfl_xor(pb, mm);
    __shared__ float red[4];
    if ((d & 63) == 0) red[d >> 6] = pb;
    __syncthreads();
    if (d == 0)
        bkv[kv * 256 + m] = red[0] + red[1] + red[2] + red[3] + aib[(kv + 1) * 256 + m];
}

// ---------------------------------------------------------------------------
// M_c = tow_c^T @ bpw_c (bilinear fold)
// ---------------------------------------------------------------------------
__global__ __launch_bounds__(256) void mcat_kernel(const float* __restrict__ tow,
                                                   const float* __restrict__ bpw,
                                                   float* __restrict__ MCAT) {
    const int cc = blockIdx.z;
    const int t0 = blockIdx.x * 16, k0 = blockIdx.y * 16;
    const int lt = threadIdx.x & 15, lj = threadIdx.x >> 4;
    const int ot = threadIdx.x & 15, ok = threadIdx.x >> 4;
    __shared__ float As[16][17], Bs[16][17];
    float acc = 0.f;
    for (int j0 = 0; j0 < 256; j0 += 16) {
        As[lj][lt] = tow[((size_t)cc * 256 + j0 + lj) * 256 + t0 + lt];
        Bs[lj][lt] = bpw[((size_t)cc * 256 + j0 + lj) * 256 + k0 + lt];
        __syncthreads();
#pragma unroll
        for (int jj = 0; jj < 16; jj++) acc += As[jj][ot] * Bs[jj][ok];
        __syncthreads();
    }
    MCAT[((size_t)cc * 256 + t0 + ot) * 256 + k0 + ok] = acc;
}

__global__ __launch_bounds__(256) void uvs_kernel(
    const float* __restrict__ tow, const float* __restrict__ tob,
    const float* __restrict__ bpw, const float* __restrict__ bpb,
    float* __restrict__ U, float* __restrict__ V, float* __restrict__ S) {
    const int cc = blockIdx.x, t = threadIdx.x;
    float v = 0.f, u = 0.f;
    for (int r = 0; r < 256; r++) {
        v += tow[((size_t)cc * 256 + r) * 256 + t] * bpb[cc * 256 + r];
        u += bpw[((size_t)cc * 256 + r) * 256 + t] * tob[cc * 256 + r];
    }
    V[cc * 256 + t] = v;
    U[cc * 256 + t] = u;
    float sp = tob[cc * 256 + t] * bpb[cc * 256 + t];
#pragma unroll
    for (int m = 32; m >= 1; m >>= 1) sp += __shfl_xor(sp, m);
    __shared__ float red[4];
    if ((t & 63) == 0) red[t >> 6] = sp;
    __syncthreads();
    if (t == 0) S[cc] = red[0] + red[1] + red[2] + red[3];
}

// ---------------------------------------------------------------------------
// per-row LN stats: S[2r]=mean, S[2r+1]=rstd. 4 rows/block.
// ---------------------------------------------------------------------------
__global__ __launch_bounds__(256) void stats_kernel(const float* __restrict__ X,
                                                    float* __restrict__ S) {
    int row = blockIdx.x * 4 + (threadIdx.x >> 6);
    int lane = threadIdx.x & 63;
    float4 v = *(const float4*)&X[(size_t)row * 256 + lane * 4];
    float s = v.x + v.y + v.z + v.w;
    float s2 = v.x * v.x + v.y * v.y + v.z * v.z + v.w * v.w;
#pragma unroll
    for (int m = 32; m >= 1; m >>= 1) {
        s += __shfl_xor(s, m);
        s2 += __shfl_xor(s2, m);
    }
    if (lane == 0) {
        float mean = s * (1.f / 256.f);
        float var = s2 * (1.f / 256.f) - mean * mean;
        S[2 * row] = mean;
        S[2 * row + 1] = rsqrtf(var + 1e-5f);
    }
}

// ---------------------------------------------------------------------------
// counting-sort of queries by IDX (512 buckets)
// ---------------------------------------------------------------------------
__global__ __launch_bounds__(256) void zcnt_kernel(int* __restrict__ cnt) {
    int i = blockIdx.x * 256 + threadIdx.x;
    if (i < TT) cnt[i] = 0;
}
__global__ __launch_bounds__(256) void hist_kernel(const int* __restrict__ IDX,
                                                   int* __restrict__ cnt) {
    int n = blockIdx.x * 256 + threadIdx.x;
    if (n < NQ) atomicAdd(&cnt[IDX[n]], 1);
}
__global__ __launch_bounds__(512) void scan_kernel(const int* __restrict__ cnt,
                                                   int* __restrict__ base,
                                                   int* __restrict__ cur) {
    __shared__ int s[TT];
    int t = threadIdx.x;
    int v = cnt[t];
    s[t] = v;
    __syncthreads();
    for (int off = 1; off < TT; off <<= 1) {
        int add = (t >= off) ? s[t - off] : 0;
        __syncthreads();
        s[t] += add;
        __syncthreads();
    }
    base[t] = s[t] - v;   // exclusive prefix
    cur[t] = s[t] - v;
}
__global__ __launch_bounds__(256) void scat_kernel(const int* __restrict__ IDX,
                                                   int* __restrict__ cur,
                                                   int* __restrict__ perm) {
    int n = blockIdx.x * 256 + threadIdx.x;
    if (n < NQ) {
        int pos = atomicAdd(&cur[IDX[n]], 1);
        perm[pos] = n;
    }
}

// ---------------------------------------------------------------------------
// MFMA bf16 GEMM (verified fragment layout), fp32 in, K=lda=256.
// ST16: store bf16. SEL: N=768; keep only component c[row].
// ---------------------------------------------------------------------------
template <int ST16, int SEL>
__global__ __launch_bounds__(256) void mgemm(
    const float* __restrict__ A, const float* __restrict__ W,
    const float* __restrict__ bias, const int* __restrict__ csel,
    void* __restrict__ Cv) {
    __shared__ u16 As[64 * 40];
    __shared__ u16 Ws[64 * 40];
    const int t = threadIdx.x;
    const size_t rb = (size_t)blockIdx.x * 64;
    const size_t cb = (size_t)blockIdx.y * 64;
    const int wave = t >> 6, lane = t & 63;
    const int m16 = lane & 15, quad = lane >> 4;
    const int sr = t >> 2, sk = (t & 3) * 8;
    const float* Ap = A + (rb + sr) * 256 + sk;
    const float* Wp = W + (cb + sr) * 256 + sk;

    f32x4 acc[4] = {};
    for (int k0 = 0; k0 < 256; k0 += 32) {
        float4 a0 = *(const float4*)(Ap + k0);
        float4 a1 = *(const float4*)(Ap + k0 + 4);
        u16 ta[8] = {f2b(a0.x), f2b(a0.y), f2b(a0.z), f2b(a0.w),
                     f2b(a1.x), f2b(a1.y), f2b(a1.z), f2b(a1.w)};
        *(uint4*)&As[sr * 40 + sk] = *(const uint4*)ta;
        float4 w0 = *(const float4*)(Wp + k0);
        float4 w1 = *(const float4*)(Wp + k0 + 4);
        u16 tb[8] = {f2b(w0.x), f2b(w0.y), f2b(w0.z), f2b(w0.w),
                     f2b(w1.x), f2b(w1.y), f2b(w1.z), f2b(w1.w)};
        *(uint4*)&Ws[sr * 40 + sk] = *(const uint4*)tb;
        __syncthreads();
        s16x8 af = *(const s16x8*)&As[(wave * 16 + m16) * 40 + quad * 8];
#pragma unroll
        for (int ct = 0; ct < 4; ct++) {
            s16x8 bf = *(const s16x8*)&Ws[(ct * 16 + m16) * 40 + quad * 8];
            acc[ct] = __builtin_amdgcn_mfma_f32_16x16x32_bf16(af, bf, acc[ct], 0, 0, 0);
        }
        __syncthreads();
    }
#pragma unroll
    for (int ct = 0; ct < 4; ct++) {
        size_t col = cb + ct * 16 + m16;
        float bb = bias ? bias[col] : 0.f;
#pragma unroll
        for (int r = 0; r < 4; r++) {
            size_t row = rb + wave * 16 + quad * 4 + r;
            float x = acc[ct][r] + bb;
            if (SEL) {
                int comp = (int)(col >> 8);
                if (csel[row] == comp)
                    ((float*)Cv)[row * 256 + (col & 255)] = x;
            } else if (ST16) {
                ((u16*)Cv)[row * 256 + col] = f2b(x);
            } else {
                ((float*)Cv)[row * 256 + col] = x;
            }
        }
    }
}

// ---------------------------------------------------------------------------
// Split-precision MFMA GEMM: A,W split into bf16 hi+lo (3 MFMAs/step) ->
// fp32-quality result. C fp32 [.,256]. LNA: LN A on load (STT,g,bln).
// ACT: silu. RES: C += old. K%32==0, lda arbitrary (row pitch).
// ---------------------------------------------------------------------------
template <int LNA, int ACT, int RES>
__global__ __launch_bounds__(256) void mgemm2(
    const float* __restrict__ A, int lda, const float* __restrict__ W,
    const float* __restrict__ bias, const float* __restrict__ st,
    const float* __restrict__ g, const float* __restrict__ bln,
    float* __restrict__ C, int K) {
    __shared__ u16 Ah[64 * 40], Al[64 * 40], Wh[64 * 40], Wl[64 * 40];
    const int t = threadIdx.x;
    const size_t rb = (size_t)blockIdx.x * 64;
    const size_t cb = (size_t)blockIdx.y * 64;
    const int wave = t >> 6, lane = t & 63;
    const int m16 = lane & 15, quad = lane >> 4;
    const int sr = t >> 2, sk = (t & 3) * 8;
    f32x4 acc[4] = {};
    for (int k0 = 0; k0 < K; k0 += 32) {
        {
            const float* p = A + (rb + sr) * (size_t)lda + k0 + sk;
            float4 v0 = *(const float4*)p;
            float4 v1 = *(const float4*)(p + 4);
            float va[8] = {v0.x, v0.y, v0.z, v0.w, v1.x, v1.y, v1.z, v1.w};
            if (LNA) {
                float mm = st[2 * (rb + sr)], ss = st[2 * (rb + sr) + 1];
#pragma unroll
                for (int e = 0; e < 8; e++)
                    va[e] = (va[e] - mm) * ss * g[k0 + sk + e] + bln[k0 + sk + e];
            }
            u16 hi[8], lo[8];
#pragma unroll
            for (int e = 0; e < 8; e++) {
                hi[e] = f2b(va[e]);
                lo[e] = f2b(va[e] - b2f(hi[e]));
            }
            *(uint4*)&Ah[sr * 40 + sk] = *(const uint4*)hi;
            *(uint4*)&Al[sr * 40 + sk] = *(const uint4*)lo;
        }
        {
            const float* p = W + (cb + sr) * (size_t)K + k0 + sk;
            float4 v0 = *(const float4*)p;
            float4 v1 = *(const float4*)(p + 4);
            float vw[8] = {v0.x, v0.y, v0.z, v0.w, v1.x, v1.y, v1.z, v1.w};
            u16 hi[8], lo[8];
#pragma unroll
            for (int e = 0; e < 8; e++) {
                hi[e] = f2b(vw[e]);
                lo[e] = f2b(vw[e] - b2f(hi[e]));
            }
            *(uint4*)&Wh[sr * 40 + sk] = *(const uint4*)hi;
            *(uint4*)&Wl[sr * 40 + sk] = *(const uint4*)lo;
        }
        __syncthreads();
        s16x8 ah = *(const s16x8*)&Ah[(wave * 16 + m16) * 40 + quad * 8];
        s16x8 al = *(const s16x8*)&Al[(wave * 16 + m16) * 40 + quad * 8];
#pragma unroll
        for (int ct = 0; ct < 4; ct++) {
            s16x8 bh = *(const s16x8*)&Wh[(ct * 16 + m16) * 40 + quad * 8];
            s16x8 bl = *(const s16x8*)&Wl[(ct * 16 + m16) * 40 + quad * 8];
            acc[ct] = __builtin_amdgcn_mfma_f32_16x16x32_bf16(ah, bh, acc[ct], 0, 0, 0);
            acc[ct] = __builtin_amdgcn_mfma_f32_16x16x32_bf16(ah, bl, acc[ct], 0, 0, 0);
            acc[ct] = __builtin_amdgcn_mfma_f32_16x16x32_bf16(al, bh, acc[ct], 0, 0, 0);
        }
        __syncthreads();
    }
#pragma unroll
    for (int ct = 0; ct < 4; ct++) {
        size_t col = cb + ct * 16 + m16;
        float bb = bias ? bias[col] : 0.f;
#pragma unroll
        for (int r = 0; r < 4; r++) {
            size_t row = rb + wave * 16 + quad * 4 + r;
            float x = acc[ct][r] + bb;
            if (ACT) x = silu_f(x);
            if (RES) x += C[row * 256 + col];
            C[row * 256 + col] = x;
        }
    }
}

// ---------------------------------------------------------------------------
// attn2: one block per time index. Loads its bf16 KV tile into LDS once
// (pitch 264 u16 to break bank conflicts), loops over that bucket's queries.
// In-place Q -> CTX.
// ---------------------------------------------------------------------------
__global__ __launch_bounds__(256) void attn2_kernel(
    float* __restrict__ QC, const u16* __restrict__ KA, const u16* __restrict__ VA,
    const int* __restrict__ base, const int* __restrict__ cnt,
    const int* __restrict__ perm) {
    __shared__ u16 ksh[STOK * 264], vsh[STOK * 264];
    __shared__ float qsh[256], scs[4][STOK], attw[4][STOK];
    const int b = blockIdx.x, t = threadIdx.x;
    const int m = cnt[b];
    if (m == 0) return;
    const size_t g0 = (size_t)b * STOK * 256;
    for (int i = t; i < STOK * 32; i += 256) {   // 32 uint4 (=256 u16) per row
        int s = i >> 5, dq = (i & 31) * 8;
        *(uint4*)&ksh[s * 264 + dq] = *(const uint4*)&KA[g0 + s * 256 + dq];
        *(uint4*)&vsh[s * 264 + dq] = *(const uint4*)&VA[g0 + s * 256 + dq];
    }
    const int n0 = base[b];
    __syncthreads();
    for (int j = 0; j < m; j++) {
        const int n = perm[n0 + j];
        qsh[t] = QC[(size_t)n * 256 + t];
        __syncthreads();
        if (t < 128) {
            int h = t >> 5, s = t & 31;
            float a = 0.f;
#pragma unroll 8
            for (int d = 0; d < 64; d++)
                a += qsh[h * 64 + d] * b2f(ksh[s * 264 + h * 64 + d]);
            scs[h][s] = a * 0.125f;
        }
        __syncthreads();
        if (t < 4) {
            float mx = -1e30f;
            for (int s = 0; s < STOK; s++) mx = fmaxf(mx, scs[t][s]);
            float sum = 0.f;
            for (int s = 0; s < STOK; s++) {
                float e = expf(scs[t][s] - mx);
                attw[t][s] = e;
                sum += e;
            }
            for (int s = 0; s < STOK; s++) attw[t][s] /= sum;
        }
        __syncthreads();
        {
            int h = t >> 6;
            float a = 0.f;
#pragma unroll 4
            for (int s = 0; s < STOK; s++) a += attw[h][s] * b2f(vsh[s * 264 + t]);
            QC[(size_t)n * 256 + t] = a;
        }
        __syncthreads();
    }
}

// ---------------------------------------------------------------------------
// final dot: out[n] = (F·H + F·v_cc + u_cc·C2 + s_cc) * exp(lt)*cs + cb
// ---------------------------------------------------------------------------
__global__ __launch_bounds__(256) void dot_kernel(
    const float* __restrict__ F, const float* __restrict__ H,
    const float* __restrict__ C2, const int* __restrict__ c,
    const float* __restrict__ U, const float* __restrict__ V,
    const float* __restrict__ S, const float* __restrict__ lt,
    const float* __restrict__ cs, const float* __restrict__ cbv,
    float* __restrict__ out) {
    const int n = blockIdx.x * 4 + (threadIdx.x >> 6);
    const int lane = threadIdx.x & 63;
    const int cc = c[n];
    float4 f4 = *(const float4*)&F[(size_t)n * 256 + lane * 4];
    float4 h4 = *(const float4*)&H[(size_t)n * 256 + lane * 4];
    float4 g4 = *(const float4*)&C2[(size_t)n * 256 + lane * 4];
    float4 v4 = *(const float4*)&V[cc * 256 + lane * 4];
    float4 u4 = *(const float4*)&U[cc * 256 + lane * 4];
    float a = f4.x * (h4.x + v4.x) + f4.y * (h4.y + v4.y) +
              f4.z * (h4.z + v4.z) + f4.w * (h4.w + v4.w) +
              u4.x * g4.x + u4.y * g4.y + u4.z * g4.z + u4.w * g4.w;
#pragma unroll
    for (int m = 32; m >= 1; m >>= 1) a += __shfl_xor(a, m);
    if (lane == 0)
        out[n] = (a + S[cc]) * expf(lt[0]) * cs[cc] + cbv[cc];
}

// ---------------------------------------------------------------------------
extern "C" void kernel_launch(void* const* d_in, const int* in_sizes, int n_in,
                              void* d_out, int out_size, void* d_ws, size_t ws_size,
                              hipStream_t stream) {
    float* out = (float*)d_out;
    const dim3 blk(256);

    static const int EXPECT[38] = {
        16384, 8192, 8192, 4194304, 512, 128, 16, 16, 24,
        38912, 256, 512, 512, 131072, 512, 131072, 512,
        65536, 256, 256, 256, 196608, 768, 65536, 256,
        256, 256, 65536, 256, 65536, 256, 196608, 768,
        196608, 768, 1, 3, 3};
    if (n_in != 38) { const_kernel<<<NQ / 256, blk, 0, stream>>>(99.0e6f, out); return; }
    for (int i = 0; i < 38; i++)
        if (in_sizes[i] != EXPECT[i]) {
            const_kernel<<<NQ / 256, blk, 0, stream>>>((100.0f + i) * 1.0e6f, out);
            return;
        }

    const float* xy  = (const float*)d_in[0];
    const float* tq  = (const float*)d_in[1];
    const int*   c   = (const int*)d_in[2];
    const float* hs  = (const float*)d_in[3];
    const float* st  = (const float*)d_in[4];
    const float* Bm  = (const float*)d_in[5];
    const float* tw  = (const float*)d_in[6];
    const float* tbv = (const float*)d_in[7];
    const float* ce  = (const float*)d_in[8];
    const float* tiw = (const float*)d_in[9];
    const float* tib = (const float*)d_in[10];
    const float* lng = (const float*)d_in[11];
    const float* lnb = (const float*)d_in[12];
    const float* f1w = (const float*)d_in[13];
    const float* f1b = (const float*)d_in[14];
    const float* f2w = (const float*)d_in[15];
    const float* f2b = (const float*)d_in[16];
    const float* btw = (const float*)d_in[17];
    const float* btb = (const float*)d_in[18];
    const float* bng = (const float*)d_in[19];
    const float* bnb = (const float*)d_in[20];
    const float* aiw = (const float*)d_in[21];
    const float* aib = (const float*)d_in[22];
    const float* aow = (const float*)d_in[23];
    const float* aob = (const float*)d_in[24];
    const float* clg = (const float*)d_in[25];
    const float* clb = (const float*)d_in[26];
    const float* w1  = (const float*)d_in[27];
    const float* b1  = (const float*)d_in[28];
    const float* w2  = (const float*)d_in[29];
    const float* b2  = (const float*)d_in[30];
    const float* tow = (const float*)d_in[31];
    const float* tob = (const float*)d_in[32];
    const float* bpw = (const float*)d_in[33];
    const float* bpb = (const float*)d_in[34];
    const float* lt  = (const float*)d_in[35];
    const float* cs  = (const float*)d_in[36];
    const float* cbv = (const float*)d_in[37];

    char* ws = (char*)d_ws;
    const size_t MB = 1 << 20;
    if (ws_size < 42 * MB) {
        const_kernel<<<NQ / 256, blk, 0, stream>>>(8.0e6f, out);
        return;
    }

    // KA [0,8) bf16; VA [8,16) bf16; S_A [16,24): FIN->Qb/CTX->H1b->H
    // S_B [24,32): F; S_C [32,40): H1->C2; misc [40,+1.6MB)
    u16*   KA   = (u16*)(ws + 0 * MB);
    u16*   VA   = (u16*)(ws + 8 * MB);
    char*  S_A  = ws + 16 * MB;
    char*  S_B  = ws + 24 * MB;
    char*  S_C  = ws + 32 * MB;
    char*  misc = ws + 40 * MB;
    float* FIN  = (float*)S_A;
    float* Qb   = (float*)S_A;
    float* H1b  = (float*)S_A;
    float* H    = (float*)S_A;
    float* F    = (float*)S_B;
    float* H1   = (float*)S_C;
    float* C2   = (float*)S_C;
    float* WPf  = (float*)misc;                       // [256,160] 160KB
    float* STT  = (float*)(misc + 160 * 1024);        // [NQ,2]   64KB
    int*   IDX  = (int*)(misc + 224 * 1024);          // 32KB
    float* WKV  = (float*)(misc + 256 * 1024);        // [2,256,256] 512KB
    float* bkv  = (float*)(misc + 768 * 1024);        // [512]
    float* MCAT = (float*)(misc + 772 * 1024);        // [768,256] 768KB
    float* Ubuf = (float*)(misc + 1540 * 1024);
    float* Vbuf = (float*)(misc + 1544 * 1024);
    float* Sbuf = (float*)(misc + 1548 * 1024);
    int*   CNT  = (int*)(misc + 1552 * 1024);         // [512]
    int*   BASE = (int*)(misc + 1556 * 1024);         // [512]
    int*   CUR  = (int*)(misc + 1560 * 1024);         // [512]
    int*   PERM = (int*)(misc + 1564 * 1024);         // [NQ] 32KB

    const dim3 gQ(NQ / 64, 4);
    const dim3 gT(TT * STOK / 64, 4);
    const dim3 gSEL(NQ / 64, 12);
    const dim3 gS(NQ / 4);

    // ---- input-only precomputation ----
    padw32_kernel<<<160, blk, 0, stream>>>(tiw, WPf);
    combine_kv32<<<512, blk, 0, stream>>>(aiw, aib, btw, btb, WKV, bkv);
    mcat_kernel<<<dim3(16, 16, 3), blk, 0, stream>>>(tow, bpw, MCAT);
    uvs_kernel<<<3, blk, 0, stream>>>(tow, tob, bpw, bpb, Ubuf, Vbuf, Sbuf);
    feat32_kernel<<<NQ, blk, 0, stream>>>(xy, tq, c, st, Bm, tw, tbv, ce, FIN, IDX);

    // ---- bucket queries by time index ----
    zcnt_kernel<<<2, blk, 0, stream>>>(CNT);
    hist_kernel<<<NQ / 256, blk, 0, stream>>>(IDX, CNT);
    scan_kernel<<<1, dim3(512), 0, stream>>>(CNT, BASE, CUR);
    scat_kernel<<<NQ / 256, blk, 0, stream>>>(IDX, CUR, PERM);

    // ---- K/V via MFMA bf16 (folded weights), stored bf16 ----
    mgemm<1, 0><<<gT, blk, 0, stream>>>(hs, WKV, bkv, nullptr, KA);
    mgemm<1, 0><<<gT, blk, 0, stream>>>(hs, WKV + 65536, bkv + 256, nullptr, VA);

    // ---- trunk (split-precision MFMA) ----
    mgemm2<0, 1, 0><<<gQ, blk, 0, stream>>>(FIN, 160, WPf, tib, nullptr, nullptr,
                                            nullptr, F, 160);
    for (int i = 0; i < 2; i++) {
        stats_kernel<<<gS, blk, 0, stream>>>(F, STT);
        mgemm2<1, 1, 0><<<gQ, blk, 0, stream>>>(F, 256, f1w + (size_t)i * 65536,
                                                f1b + i * 256, STT, lng + i * 256,
                                                lnb + i * 256, H1, 256);
        mgemm2<0, 0, 1><<<gQ, blk, 0, stream>>>(H1, 256, f2w + (size_t)i * 65536,
                                                f2b + i * 256, nullptr, nullptr,
                                                nullptr, F, 256);
    }
    // ---- q projection ----
    stats_kernel<<<gS, blk, 0, stream>>>(F, STT);
    mgemm2<1, 0, 0><<<gQ, blk, 0, stream>>>(F, 256, aiw, aib, STT, bng, bnb, Qb, 256);
    // ---- attention (bucketed, in-place Qb -> CTX) ----
    attn2_kernel<<<TT, blk, 0, stream>>>(Qb, KA, VA, BASE, CNT, PERM);
    // ---- attn_out ----
    mgemm2<0, 0, 0><<<gQ, blk, 0, stream>>>(Qb, 256, aow, aob, nullptr, nullptr,
                                            nullptr, C2, 256);
    // ---- bc correction block ----
    stats_kernel<<<gS, blk, 0, stream>>>(C2, STT);
    mgemm2<1, 1, 0><<<gQ, blk, 0, stream>>>(C2, 256, w1, b1, STT, clg, clb, H1b, 256);
    mgemm2<0, 0, 1><<<gQ, blk, 0, stream>>>(H1b, 256, w2, b2, nullptr, nullptr,
                                            nullptr, C2, 256);
    // ---- H[n] = M_{c[n]} @ C2[n] via MFMA SEL ----
    mgemm<0, 1><<<gSEL, blk, 0, stream>>>(C2, MCAT, nullptr, c, H);
    // ---- final dot ----
    dot_kernel<<<NQ / 4, blk, 0, stream>>>(F, H, C2, c, Ubuf, Vbuf, Sbuf, lt, cs, cbv, out);
}

// Round 14
// 438.425 us; speedup vs baseline: 1.8884x; 1.8884x over previous
//
#include <hip/hip_runtime.h>
#include <cstdint>
#include <cstddef>

typedef unsigned short u16;
typedef __attribute__((ext_vector_type(8))) short s16x8;
typedef __attribute__((ext_vector_type(4))) float f32x4;

#define NQ   8192
#define TT   512
#define STOK 32

__device__ __forceinline__ float b2f(u16 u) {
    return __uint_as_float(((uint32_t)u) << 16);
}
__device__ __forceinline__ u16 f2b(float f) {
    uint32_t x = __float_as_uint(f);
    uint32_t r = (x + 0x7FFFu + ((x >> 16) & 1u)) >> 16;
    return (u16)r;
}
__device__ __forceinline__ float silu_f(float x) { return x / (1.f + expf(-x)); }

__global__ __launch_bounds__(256) void const_kernel(float v, float* __restrict__ out) {
    int i = blockIdx.x * 256 + threadIdx.x;
    if (i < NQ) out[i] = v;
}

// ---------------------------------------------------------------------------
// features (verified): FIN fp32 [NQ,160] (cols 152..159 = 0), IDX
// ---------------------------------------------------------------------------
__global__ __launch_bounds__(256) void feat32_kernel(
    const float* __restrict__ xy, const float* __restrict__ t_q,
    const int* __restrict__ c, const float* __restrict__ st,
    const float* __restrict__ B, const float* __restrict__ tw,
    const float* __restrict__ tb, const float* __restrict__ ce,
    float* __restrict__ FIN, int* __restrict__ IDX) {
    int n = blockIdx.x, t = threadIdx.x;
    float tq = t_q[n];
    int lo = 0, hi = TT;
    while (lo < hi) {
        int mid = (lo + hi) >> 1;
        if (st[mid] <= tq) lo = mid + 1; else hi = mid;
    }
    int idx = lo - 1;
    if (idx < 0) idx = 0;
    float dt = tq - st[idx];
    if (dt < 0.f) dt = 0.f;
    if (t == 0) IDX[n] = idx;
    float x = xy[2 * n], y = xy[2 * n + 1];
    size_t base = (size_t)n * 160;
    if (t < 64) { float p = x * B[t] + y * B[64 + t]; FIN[base + t] = cosf(p); }
    else if (t < 128) { int j = t - 64; float p = x * B[j] + y * B[64 + j]; FIN[base + t] = sinf(p); }
    else if (t < 144) { int j = t - 128; FIN[base + t] = dt * tw[j] + tb[j]; }
    else if (t < 152) { int j = t - 144; FIN[base + t] = ce[c[n] * 8 + j]; }
    else if (t < 160) { FIN[base + t] = 0.f; }
}

// pad trunk_in_w [256,152] -> [256,160] fp32
__global__ __launch_bounds__(256) void padw32_kernel(const float* __restrict__ w,
                                                     float* __restrict__ wp) {
    int i = blockIdx.x * 256 + threadIdx.x;
    if (i < 256 * 160) {
        int r = i / 160, k = i % 160;
        wp[i] = (k < 152) ? w[r * 152 + k] : 0.f;
    }
}

// ---------------------------------------------------------------------------
// fold token projection into K/V weights (exact identity, fp32)
// ---------------------------------------------------------------------------
__global__ __launch_bounds__(256) void combine_kv32(
    const float* __restrict__ aiw, const float* __restrict__ aib,
    const float* __restrict__ btw, const float* __restrict__ btb,
    float* __restrict__ WKV, float* __restrict__ bkv) {
    int kv = blockIdx.x >> 8, m = blockIdx.x & 255;
    int d = threadIdx.x;
    __shared__ float wrow[256];
    wrow[d] = aiw[(size_t)(kv + 1) * 65536 + (size_t)m * 256 + d];
    __syncthreads();
    float acc = 0.f;
#pragma unroll 8
    for (int o = 0; o < 256; o++) acc += wrow[o] * btw[(size_t)o * 256 + d];
    WKV[(size_t)kv * 65536 + (size_t)m * 256 + d] = acc;
    float pb = wrow[d] * btb[d];
#pragma unroll
    for (int mm = 32; mm >= 1; mm >>= 1) pb += __shfl_xor(pb, mm);
    __shared__ float red[4];
    if ((d & 63) == 0) red[d >> 6] = pb;
    __syncthreads();
    if (d == 0)
        bkv[kv * 256 + m] = red[0] + red[1] + red[2] + red[3] + aib[(kv + 1) * 256 + m];
}

// ---------------------------------------------------------------------------
// M_c = tow_c^T @ bpw_c (bilinear fold)
// ---------------------------------------------------------------------------
__global__ __launch_bounds__(256) void mcat_kernel(const float* __restrict__ tow,
                                                   const float* __restrict__ bpw,
                                                   float* __restrict__ MCAT) {
    const int cc = blockIdx.z;
    const int t0 = blockIdx.x * 16, k0 = blockIdx.y * 16;
    const int lt = threadIdx.x & 15, lj = threadIdx.x >> 4;
    const int ot = threadIdx.x & 15, ok = threadIdx.x >> 4;
    __shared__ float As[16][17], Bs[16][17];
    float acc = 0.f;
    for (int j0 = 0; j0 < 256; j0 += 16) {
        As[lj][lt] = tow[((size_t)cc * 256 + j0 + lj) * 256 + t0 + lt];
        Bs[lj][lt] = bpw[((size_t)cc * 256 + j0 + lj) * 256 + k0 + lt];
        __syncthreads();
#pragma unroll
        for (int jj = 0; jj < 16; jj++) acc += As[jj][ot] * Bs[jj][ok];
        __syncthreads();
    }
    MCAT[((size_t)cc * 256 + t0 + ot) * 256 + k0 + ok] = acc;
}

__global__ __launch_bounds__(256) void uvs_kernel(
    const float* __restrict__ tow, const float* __restrict__ tob,
    const float* __restrict__ bpw, const float* __restrict__ bpb,
    float* __restrict__ U, float* __restrict__ V, float* __restrict__ S) {
    const int cc = blockIdx.x, t = threadIdx.x;
    float v = 0.f, u = 0.f;
    for (int r = 0; r < 256; r++) {
        v += tow[((size_t)cc * 256 + r) * 256 + t] * bpb[cc * 256 + r];
        u += bpw[((size_t)cc * 256 + r) * 256 + t] * tob[cc * 256 + r];
    }
    V[cc * 256 + t] = v;
    U[cc * 256 + t] = u;
    float sp = tob[cc * 256 + t] * bpb[cc * 256 + t];
#pragma unroll
    for (int m = 32; m >= 1; m >>= 1) sp += __shfl_xor(sp, m);
    __shared__ float red[4];
    if ((t & 63) == 0) red[t >> 6] = sp;
    __syncthreads();
    if (t == 0) S[cc] = red[0] + red[1] + red[2] + red[3];
}

// ---------------------------------------------------------------------------
// per-row LN stats: S[2r]=mean, S[2r+1]=rstd. 4 rows/block.
// ---------------------------------------------------------------------------
__global__ __launch_bounds__(256) void stats_kernel(const float* __restrict__ X,
                                                    float* __restrict__ S) {
    int row = blockIdx.x * 4 + (threadIdx.x >> 6);
    int lane = threadIdx.x & 63;
    float4 v = *(const float4*)&X[(size_t)row * 256 + lane * 4];
    float s = v.x + v.y + v.z + v.w;
    float s2 = v.x * v.x + v.y * v.y + v.z * v.z + v.w * v.w;
#pragma unroll
    for (int m = 32; m >= 1; m >>= 1) {
        s += __shfl_xor(s, m);
        s2 += __shfl_xor(s2, m);
    }
    if (lane == 0) {
        float mean = s * (1.f / 256.f);
        float var = s2 * (1.f / 256.f) - mean * mean;
        S[2 * row] = mean;
        S[2 * row + 1] = rsqrtf(var + 1e-5f);
    }
}

// ---------------------------------------------------------------------------
// counting-sort of queries by IDX (512 buckets) -> perm (L2-locality order)
// ---------------------------------------------------------------------------
__global__ __launch_bounds__(256) void zcnt_kernel(int* __restrict__ cnt) {
    int i = blockIdx.x * 256 + threadIdx.x;
    if (i < TT) cnt[i] = 0;
}
__global__ __launch_bounds__(256) void hist_kernel(const int* __restrict__ IDX,
                                                   int* __restrict__ cnt) {
    int n = blockIdx.x * 256 + threadIdx.x;
    if (n < NQ) atomicAdd(&cnt[IDX[n]], 1);
}
__global__ __launch_bounds__(512) void scan_kernel(const int* __restrict__ cnt,
                                                   int* __restrict__ base,
                                                   int* __restrict__ cur) {
    __shared__ int s[TT];
    int t = threadIdx.x;
    int v = cnt[t];
    s[t] = v;
    __syncthreads();
    for (int off = 1; off < TT; off <<= 1) {
        int add = (t >= off) ? s[t - off] : 0;
        __syncthreads();
        s[t] += add;
        __syncthreads();
    }
    base[t] = s[t] - v;   // exclusive prefix
    cur[t] = s[t] - v;
}
__global__ __launch_bounds__(256) void scat_kernel(const int* __restrict__ IDX,
                                                   int* __restrict__ cur,
                                                   int* __restrict__ perm) {
    int n = blockIdx.x * 256 + threadIdx.x;
    if (n < NQ) {
        int pos = atomicAdd(&cur[IDX[n]], 1);
        perm[pos] = n;
    }
}

// ---------------------------------------------------------------------------
// MFMA bf16 GEMM (verified fragment layout), fp32 in, K=lda=256.
// ST16: store bf16. SEL: N=768; keep only component c[row].
// ---------------------------------------------------------------------------
template <int ST16, int SEL>
__global__ __launch_bounds__(256) void mgemm(
    const float* __restrict__ A, const float* __restrict__ W,
    const float* __restrict__ bias, const int* __restrict__ csel,
    void* __restrict__ Cv) {
    __shared__ u16 As[64 * 40];
    __shared__ u16 Ws[64 * 40];
    const int t = threadIdx.x;
    const size_t rb = (size_t)blockIdx.x * 64;
    const size_t cb = (size_t)blockIdx.y * 64;
    const int wave = t >> 6, lane = t & 63;
    const int m16 = lane & 15, quad = lane >> 4;
    const int sr = t >> 2, sk = (t & 3) * 8;
    const float* Ap = A + (rb + sr) * 256 + sk;
    const float* Wp = W + (cb + sr) * 256 + sk;

    f32x4 acc[4] = {};
    for (int k0 = 0; k0 < 256; k0 += 32) {
        float4 a0 = *(const float4*)(Ap + k0);
        float4 a1 = *(const float4*)(Ap + k0 + 4);
        u16 ta[8] = {f2b(a0.x), f2b(a0.y), f2b(a0.z), f2b(a0.w),
                     f2b(a1.x), f2b(a1.y), f2b(a1.z), f2b(a1.w)};
        *(uint4*)&As[sr * 40 + sk] = *(const uint4*)ta;
        float4 w0 = *(const float4*)(Wp + k0);
        float4 w1 = *(const float4*)(Wp + k0 + 4);
        u16 tb[8] = {f2b(w0.x), f2b(w0.y), f2b(w0.z), f2b(w0.w),
                     f2b(w1.x), f2b(w1.y), f2b(w1.z), f2b(w1.w)};
        *(uint4*)&Ws[sr * 40 + sk] = *(const uint4*)tb;
        __syncthreads();
        s16x8 af = *(const s16x8*)&As[(wave * 16 + m16) * 40 + quad * 8];
#pragma unroll
        for (int ct = 0; ct < 4; ct++) {
            s16x8 bf = *(const s16x8*)&Ws[(ct * 16 + m16) * 40 + quad * 8];
            acc[ct] = __builtin_amdgcn_mfma_f32_16x16x32_bf16(af, bf, acc[ct], 0, 0, 0);
        }
        __syncthreads();
    }
#pragma unroll
    for (int ct = 0; ct < 4; ct++) {
        size_t col = cb + ct * 16 + m16;
        float bb = bias ? bias[col] : 0.f;
#pragma unroll
        for (int r = 0; r < 4; r++) {
            size_t row = rb + wave * 16 + quad * 4 + r;
            float x = acc[ct][r] + bb;
            if (SEL) {
                int comp = (int)(col >> 8);
                if (csel[row] == comp)
                    ((float*)Cv)[row * 256 + (col & 255)] = x;
            } else if (ST16) {
                ((u16*)Cv)[row * 256 + col] = f2b(x);
            } else {
                ((float*)Cv)[row * 256 + col] = x;
            }
        }
    }
}

// ---------------------------------------------------------------------------
// Split-precision MFMA GEMM: A,W split into bf16 hi+lo (3 MFMAs/step) ->
// fp32-quality result. C fp32 [.,256]. LNA: LN A on load (STT,g,bln).
// ACT: silu. RES: C += old. K%32==0, lda arbitrary (row pitch).
// ---------------------------------------------------------------------------
template <int LNA, int ACT, int RES>
__global__ __launch_bounds__(256) void mgemm2(
    const float* __restrict__ A, int lda, const float* __restrict__ W,
    const float* __restrict__ bias, const float* __restrict__ st,
    const float* __restrict__ g, const float* __restrict__ bln,
    float* __restrict__ C, int K) {
    __shared__ u16 Ah[64 * 40], Al[64 * 40], Wh[64 * 40], Wl[64 * 40];
    const int t = threadIdx.x;
    const size_t rb = (size_t)blockIdx.x * 64;
    const size_t cb = (size_t)blockIdx.y * 64;
    const int wave = t >> 6, lane = t & 63;
    const int m16 = lane & 15, quad = lane >> 4;
    const int sr = t >> 2, sk = (t & 3) * 8;
    f32x4 acc[4] = {};
    for (int k0 = 0; k0 < K; k0 += 32) {
        {
            const float* p = A + (rb + sr) * (size_t)lda + k0 + sk;
            float4 v0 = *(const float4*)p;
            float4 v1 = *(const float4*)(p + 4);
            float va[8] = {v0.x, v0.y, v0.z, v0.w, v1.x, v1.y, v1.z, v1.w};
            if (LNA) {
                float mm = st[2 * (rb + sr)], ss = st[2 * (rb + sr) + 1];
#pragma unroll
                for (int e = 0; e < 8; e++)
                    va[e] = (va[e] - mm) * ss * g[k0 + sk + e] + bln[k0 + sk + e];
            }
            u16 hi[8], lo[8];
#pragma unroll
            for (int e = 0; e < 8; e++) {
                hi[e] = f2b(va[e]);
                lo[e] = f2b(va[e] - b2f(hi[e]));
            }
            *(uint4*)&Ah[sr * 40 + sk] = *(const uint4*)hi;
            *(uint4*)&Al[sr * 40 + sk] = *(const uint4*)lo;
        }
        {
            const float* p = W + (cb + sr) * (size_t)K + k0 + sk;
            float4 v0 = *(const float4*)p;
            float4 v1 = *(const float4*)(p + 4);
            float vw[8] = {v0.x, v0.y, v0.z, v0.w, v1.x, v1.y, v1.z, v1.w};
            u16 hi[8], lo[8];
#pragma unroll
            for (int e = 0; e < 8; e++) {
                hi[e] = f2b(vw[e]);
                lo[e] = f2b(vw[e] - b2f(hi[e]));
            }
            *(uint4*)&Wh[sr * 40 + sk] = *(const uint4*)hi;
            *(uint4*)&Wl[sr * 40 + sk] = *(const uint4*)lo;
        }
        __syncthreads();
        s16x8 ah = *(const s16x8*)&Ah[(wave * 16 + m16) * 40 + quad * 8];
        s16x8 al = *(const s16x8*)&Al[(wave * 16 + m16) * 40 + quad * 8];
#pragma unroll
        for (int ct = 0; ct < 4; ct++) {
            s16x8 bh = *(const s16x8*)&Wh[(ct * 16 + m16) * 40 + quad * 8];
            s16x8 bl = *(const s16x8*)&Wl[(ct * 16 + m16) * 40 + quad * 8];
            acc[ct] = __builtin_amdgcn_mfma_f32_16x16x32_bf16(ah, bh, acc[ct], 0, 0, 0);
            acc[ct] = __builtin_amdgcn_mfma_f32_16x16x32_bf16(ah, bl, acc[ct], 0, 0, 0);
            acc[ct] = __builtin_amdgcn_mfma_f32_16x16x32_bf16(al, bh, acc[ct], 0, 0, 0);
        }
        __syncthreads();
    }
#pragma unroll
    for (int ct = 0; ct < 4; ct++) {
        size_t col = cb + ct * 16 + m16;
        float bb = bias ? bias[col] : 0.f;
#pragma unroll
        for (int r = 0; r < 4; r++) {
            size_t row = rb + wave * 16 + quad * 4 + r;
            float x = acc[ct][r] + bb;
            if (ACT) x = silu_f(x);
            if (RES) x += C[row * 256 + col];
            C[row * 256 + col] = x;
        }
    }
}

// ---------------------------------------------------------------------------
// attn3: one block per query, block b -> query perm[b] (sorted by time index
// for L2 locality of the bf16 KV tiles). In-place Qb -> CTX.
// ---------------------------------------------------------------------------
__global__ __launch_bounds__(256) void attn3_kernel(
    float* __restrict__ QC, const u16* __restrict__ KA, const u16* __restrict__ VA,
    const int* __restrict__ idx, const int* __restrict__ perm) {
    __shared__ float qsh[256], scs[4][STOK], attw[4][STOK];
    const int n = perm[blockIdx.x];
    const int t = threadIdx.x;
    qsh[t] = QC[(size_t)n * 256 + t];
    int ii = idx[n];
    ii = ii < 0 ? 0 : (ii > TT - 1 ? TT - 1 : ii);
    const size_t base = (size_t)ii * STOK * 256;
    __syncthreads();
    if (t < 128) {
        int h = t >> 5, s = t & 31;
        float a = 0.f;
#pragma unroll 8
        for (int d = 0; d < 64; d++)
            a += qsh[h * 64 + d] * b2f(KA[base + (size_t)s * 256 + h * 64 + d]);
        scs[h][s] = a * 0.125f;
    }
    __syncthreads();
    if (t < 4) {
        float mx = -1e30f;
        for (int s = 0; s < STOK; s++) mx = fmaxf(mx, scs[t][s]);
        float sum = 0.f;
        for (int s = 0; s < STOK; s++) { float e = expf(scs[t][s] - mx); attw[t][s] = e; sum += e; }
        for (int s = 0; s < STOK; s++) attw[t][s] /= sum;
    }
    __syncthreads();
    {
        int h = t >> 6;
        float a = 0.f;
#pragma unroll 4
        for (int s = 0; s < STOK; s++)
            a += attw[h][s] * b2f(VA[base + (size_t)s * 256 + t]);
        QC[(size_t)n * 256 + t] = a;
    }
}

// ---------------------------------------------------------------------------
// final dot: out[n] = (F·H + F·v_cc + u_cc·C2 + s_cc) * exp(lt)*cs + cb
// ---------------------------------------------------------------------------
__global__ __launch_bounds__(256) void dot_kernel(
    const float* __restrict__ F, const float* __restrict__ H,
    const float* __restrict__ C2, const int* __restrict__ c,
    const float* __restrict__ U, const float* __restrict__ V,
    const float* __restrict__ S, const float* __restrict__ lt,
    const float* __restrict__ cs, const float* __restrict__ cbv,
    float* __restrict__ out) {
    const int n = blockIdx.x * 4 + (threadIdx.x >> 6);
    const int lane = threadIdx.x & 63;
    const int cc = c[n];
    float4 f4 = *(const float4*)&F[(size_t)n * 256 + lane * 4];
    float4 h4 = *(const float4*)&H[(size_t)n * 256 + lane * 4];
    float4 g4 = *(const float4*)&C2[(size_t)n * 256 + lane * 4];
    float4 v4 = *(const float4*)&V[cc * 256 + lane * 4];
    float4 u4 = *(const float4*)&U[cc * 256 + lane * 4];
    float a = f4.x * (h4.x + v4.x) + f4.y * (h4.y + v4.y) +
              f4.z * (h4.z + v4.z) + f4.w * (h4.w + v4.w) +
              u4.x * g4.x + u4.y * g4.y + u4.z * g4.z + u4.w * g4.w;
#pragma unroll
    for (int m = 32; m >= 1; m >>= 1) a += __shfl_xor(a, m);
    if (lane == 0)
        out[n] = (a + S[cc]) * expf(lt[0]) * cs[cc] + cbv[cc];
}

// ---------------------------------------------------------------------------
extern "C" void kernel_launch(void* const* d_in, const int* in_sizes, int n_in,
                              void* d_out, int out_size, void* d_ws, size_t ws_size,
                              hipStream_t stream) {
    float* out = (float*)d_out;
    const dim3 blk(256);

    static const int EXPECT[38] = {
        16384, 8192, 8192, 4194304, 512, 128, 16, 16, 24,
        38912, 256, 512, 512, 131072, 512, 131072, 512,
        65536, 256, 256, 256, 196608, 768, 65536, 256,
        256, 256, 65536, 256, 65536, 256, 196608, 768,
        196608, 768, 1, 3, 3};
    if (n_in != 38) { const_kernel<<<NQ / 256, blk, 0, stream>>>(99.0e6f, out); return; }
    for (int i = 0; i < 38; i++)
        if (in_sizes[i] != EXPECT[i]) {
            const_kernel<<<NQ / 256, blk, 0, stream>>>((100.0f + i) * 1.0e6f, out);
            return;
        }

    const float* xy  = (const float*)d_in[0];
    const float* tq  = (const float*)d_in[1];
    const int*   c   = (const int*)d_in[2];
    const float* hs  = (const float*)d_in[3];
    const float* st  = (const float*)d_in[4];
    const float* Bm  = (const float*)d_in[5];
    const float* tw  = (const float*)d_in[6];
    const float* tbv = (const float*)d_in[7];
    const float* ce  = (const float*)d_in[8];
    const float* tiw = (const float*)d_in[9];
    const float* tib = (const float*)d_in[10];
    const float* lng = (const float*)d_in[11];
    const float* lnb = (const float*)d_in[12];
    const float* f1w = (const float*)d_in[13];
    const float* f1b = (const float*)d_in[14];
    const float* f2w = (const float*)d_in[15];
    const float* f2b = (const float*)d_in[16];
    const float* btw = (const float*)d_in[17];
    const float* btb = (const float*)d_in[18];
    const float* bng = (const float*)d_in[19];
    const float* bnb = (const float*)d_in[20];
    const float* aiw = (const float*)d_in[21];
    const float* aib = (const float*)d_in[22];
    const float* aow = (const float*)d_in[23];
    const float* aob = (const float*)d_in[24];
    const float* clg = (const float*)d_in[25];
    const float* clb = (const float*)d_in[26];
    const float* w1  = (const float*)d_in[27];
    const float* b1  = (const float*)d_in[28];
    const float* w2  = (const float*)d_in[29];
    const float* b2  = (const float*)d_in[30];
    const float* tow = (const float*)d_in[31];
    const float* tob = (const float*)d_in[32];
    const float* bpw = (const float*)d_in[33];
    const float* bpb = (const float*)d_in[34];
    const float* lt  = (const float*)d_in[35];
    const float* cs  = (const float*)d_in[36];
    const float* cbv = (const float*)d_in[37];

    char* ws = (char*)d_ws;
    const size_t MB = 1 << 20;
    if (ws_size < 42 * MB) {
        const_kernel<<<NQ / 256, blk, 0, stream>>>(8.0e6f, out);
        return;
    }

    u16*   KA   = (u16*)(ws + 0 * MB);
    u16*   VA   = (u16*)(ws + 8 * MB);
    char*  S_A  = ws + 16 * MB;
    char*  S_B  = ws + 24 * MB;
    char*  S_C  = ws + 32 * MB;
    char*  misc = ws + 40 * MB;
    float* FIN  = (float*)S_A;
    float* Qb   = (float*)S_A;
    float* H1b  = (float*)S_A;
    float* H    = (float*)S_A;
    float* F    = (float*)S_B;
    float* H1   = (float*)S_C;
    float* C2   = (float*)S_C;
    float* WPf  = (float*)misc;                       // [256,160] 160KB
    float* STT  = (float*)(misc + 160 * 1024);        // [NQ,2]   64KB
    int*   IDX  = (int*)(misc + 224 * 1024);          // 32KB
    float* WKV  = (float*)(misc + 256 * 1024);        // [2,256,256] 512KB
    float* bkv  = (float*)(misc + 768 * 1024);        // [512]
    float* MCAT = (float*)(misc + 772 * 1024);        // [768,256] 768KB
    float* Ubuf = (float*)(misc + 1540 * 1024);
    float* Vbuf = (float*)(misc + 1544 * 1024);
    float* Sbuf = (float*)(misc + 1548 * 1024);
    int*   CNT  = (int*)(misc + 1552 * 1024);
    int*   BASE = (int*)(misc + 1556 * 1024);
    int*   CUR  = (int*)(misc + 1560 * 1024);
    int*   PERM = (int*)(misc + 1564 * 1024);         // [NQ] 32KB

    const dim3 gQ(NQ / 64, 4);
    const dim3 gT(TT * STOK / 64, 4);
    const dim3 gSEL(NQ / 64, 12);
    const dim3 gS(NQ / 4);

    // ---- input-only precomputation ----
    padw32_kernel<<<160, blk, 0, stream>>>(tiw, WPf);
    combine_kv32<<<512, blk, 0, stream>>>(aiw, aib, btw, btb, WKV, bkv);
    mcat_kernel<<<dim3(16, 16, 3), blk, 0, stream>>>(tow, bpw, MCAT);
    uvs_kernel<<<3, blk, 0, stream>>>(tow, tob, bpw, bpb, Ubuf, Vbuf, Sbuf);
    feat32_kernel<<<NQ, blk, 0, stream>>>(xy, tq, c, st, Bm, tw, tbv, ce, FIN, IDX);

    // ---- bucket queries by time index (for perm ordering) ----
    zcnt_kernel<<<2, blk, 0, stream>>>(CNT);
    hist_kernel<<<NQ / 256, blk, 0, stream>>>(IDX, CNT);
    scan_kernel<<<1, dim3(512), 0, stream>>>(CNT, BASE, CUR);
    scat_kernel<<<NQ / 256, blk, 0, stream>>>(IDX, CUR, PERM);

    // ---- K/V via MFMA bf16 (folded weights), stored bf16 ----
    mgemm<1, 0><<<gT, blk, 0, stream>>>(hs, WKV, bkv, nullptr, KA);
    mgemm<1, 0><<<gT, blk, 0, stream>>>(hs, WKV + 65536, bkv + 256, nullptr, VA);

    // ---- trunk (split-precision MFMA) ----
    mgemm2<0, 1, 0><<<gQ, blk, 0, stream>>>(FIN, 160, WPf, tib, nullptr, nullptr,
                                            nullptr, F, 160);
    for (int i = 0; i < 2; i++) {
        stats_kernel<<<gS, blk, 0, stream>>>(F, STT);
        mgemm2<1, 1, 0><<<gQ, blk, 0, stream>>>(F, 256, f1w + (size_t)i * 65536,
                                                f1b + i * 256, STT, lng + i * 256,
                                                lnb + i * 256, H1, 256);
        mgemm2<0, 0, 1><<<gQ, blk, 0, stream>>>(H1, 256, f2w + (size_t)i * 65536,
                                                f2b + i * 256, nullptr, nullptr,
                                                nullptr, F, 256);
    }
    // ---- q projection ----
    stats_kernel<<<gS, blk, 0, stream>>>(F, STT);
    mgemm2<1, 0, 0><<<gQ, blk, 0, stream>>>(F, 256, aiw, aib, STT, bng, bnb, Qb, 256);
    // ---- attention (per-query blocks, perm-ordered for L2 locality) ----
    attn3_kernel<<<NQ, blk, 0, stream>>>(Qb, KA, VA, IDX, PERM);
    // ---- attn_out ----
    mgemm2<0, 0, 0><<<gQ, blk, 0, stream>>>(Qb, 256, aow, aob, nullptr, nullptr,
                                            nullptr, C2, 256);
    // ---- bc correction block ----
    stats_kernel<<<gS, blk, 0, stream>>>(C2, STT);
    mgemm2<1, 1, 0><<<gQ, blk, 0, stream>>>(C2, 256, w1, b1, STT, clg, clb, H1b, 256);
    mgemm2<0, 0, 1><<<gQ, blk, 0, stream>>>(H1b, 256, w2, b2, nullptr, nullptr,
                                            nullptr, C2, 256);
    // ---- H[n] = M_{c[n]} @ C2[n] via MFMA SEL ----
    mgemm<0, 1><<<gSEL, blk, 0, stream>>>(C2, MCAT, nullptr, c, H);
    // ---- final dot ----
    dot_kernel<<<NQ / 4, blk, 0, stream>>>(F, H, C2, c, Ubuf, Vbuf, Sbuf, lt, cs, cbv, out);
}